// Round 1
// baseline (168.162 us; speedup 1.0000x reference)
//
#include <hip/hip_runtime.h>
#include <hip/hip_bf16.h>

// RBFNet forward, MI355X (gfx950).
// out[i] = sigmoid( b + sum_c w[c] * exp( x[i].c[c] - 0.5*(||x_i||^2 + ||c_c||^2) ) )
// Cross term via bf16 MFMA 16x16x32; everything else fused.

#define BATCH 16384
#define NCENT 4096
#define KDIM  256

#define BM 128
#define BN 128
#define LDT 264   // LDS row length in bf16 elems: 256 + 8 pad (528B stride, 16B aligned)

using f32x4 = __attribute__((ext_vector_type(4))) float;
using s16x8 = __attribute__((ext_vector_type(8))) short;

__device__ __forceinline__ unsigned short f2bf(float f) {
  // round-to-nearest-even fp32 -> bf16 (inputs are finite gaussians; no NaN path needed)
  unsigned int u = __float_as_uint(f);
  return (unsigned short)((u + 0x7FFFu + ((u >> 16) & 1u)) >> 16);
}

__launch_bounds__(512, 1)
__global__ void rbf_gemm(const float* __restrict__ x,
                         const float* __restrict__ cent,
                         const float* __restrict__ w,
                         float* __restrict__ part) {
  __shared__ unsigned short As[BM][LDT];   // x tile, bf16 bits
  __shared__ unsigned short Bs[BN][LDT];   // centers tile, bf16 bits
  __shared__ float xsq[BM], csq[BN], wsh[BN], psum[BM];

  const int tid = threadIdx.x;
  const int r0  = blockIdx.y * BM;   // batch rows
  const int c0  = blockIdx.x * BN;   // center cols

  if (tid < BM) { xsq[tid] = 0.f; psum[tid] = 0.f; }
  else if (tid < BM + BN) { csq[tid - BM] = 0.f; }
  if (tid < BN) wsh[tid] = w[c0 + tid];
  __syncthreads();

  // ---- stage x tile: fp32 -> bf16 into LDS, accumulate row sum-of-squares ----
  {
    const int row = tid >> 2, q = tid & 3;            // 4 threads per row
    const float4* src = (const float4*)(x + (size_t)(r0 + row) * KDIM);
    float s = 0.f;
#pragma unroll
    for (int i = 0; i < 16; ++i) {
      const int c4 = q + 4 * i;                       // float4 index in row (0..63)
      float4 v = src[c4];
      s += v.x * v.x + v.y * v.y + v.z * v.z + v.w * v.w;
      ushort4 u = { f2bf(v.x), f2bf(v.y), f2bf(v.z), f2bf(v.w) };
      *(ushort4*)&As[row][c4 * 4] = u;                // ds_write_b64
    }
    atomicAdd(&xsq[row], s);
  }
  // ---- stage centers tile, same pattern ----
  {
    const int row = tid >> 2, q = tid & 3;
    const float4* src = (const float4*)(cent + (size_t)(c0 + row) * KDIM);
    float s = 0.f;
#pragma unroll
    for (int i = 0; i < 16; ++i) {
      const int c4 = q + 4 * i;
      float4 v = src[c4];
      s += v.x * v.x + v.y * v.y + v.z * v.z + v.w * v.w;
      ushort4 u = { f2bf(v.x), f2bf(v.y), f2bf(v.z), f2bf(v.w) };
      *(ushort4*)&Bs[row][c4 * 4] = u;
    }
    atomicAdd(&csq[row], s);
  }
  __syncthreads();

  // ---- MFMA compute: 8 waves as 2(M) x 4(N); wave tile 64x32 = 4x2 frags ----
  const int wid = tid >> 6, lane = tid & 63;
  const int wm = wid >> 2, wn = wid & 3;
  const int lr = lane & 15;          // A-row / B-col within frag
  const int kg = lane >> 4;          // k-group (8 contiguous bf16 per lane)

  f32x4 acc[4][2];
#pragma unroll
  for (int m = 0; m < 4; ++m)
#pragma unroll
    for (int n = 0; n < 2; ++n)
      acc[m][n] = f32x4{0.f, 0.f, 0.f, 0.f};

#pragma unroll
  for (int ks = 0; ks < 8; ++ks) {   // K = 256 = 8 * 32
    const int kb = ks * 32 + kg * 8;
    s16x8 af[4], bfr[2];
#pragma unroll
    for (int m = 0; m < 4; ++m)
      af[m] = *(const s16x8*)&As[wm * 64 + m * 16 + lr][kb];   // ds_read_b128
#pragma unroll
    for (int n = 0; n < 2; ++n)
      bfr[n] = *(const s16x8*)&Bs[wn * 32 + n * 16 + lr][kb];
#pragma unroll
    for (int m = 0; m < 4; ++m)
#pragma unroll
      for (int n = 0; n < 2; ++n)
        acc[m][n] = __builtin_amdgcn_mfma_f32_16x16x32_bf16(af[m], bfr[n], acc[m][n], 0, 0, 0);
  }

  // ---- epilogue: phi = exp(acc - 0.5*(xsq+csq)); v = w*phi; row-reduce; psum ----
  const float LOG2E = 1.44269504088896340736f;
#pragma unroll
  for (int m = 0; m < 4; ++m) {
    const int rbase = wm * 64 + m * 16 + kg * 4;   // C/D: row = (lane>>4)*4 + reg
#pragma unroll
    for (int r = 0; r < 4; ++r) {
      const float hx = xsq[rbase + r];
      float v = 0.f;
#pragma unroll
      for (int n = 0; n < 2; ++n) {
        const int col = wn * 32 + n * 16 + lr;     // C/D: col = lane&15
        const float e = acc[m][n][r] - 0.5f * (hx + csq[col]);
        v += wsh[col] * exp2f(e * LOG2E);
      }
      // reduce across the 16 lanes (same row, 16 cols)
      v += __shfl_xor(v, 1);
      v += __shfl_xor(v, 2);
      v += __shfl_xor(v, 4);
      v += __shfl_xor(v, 8);
      if (lr == 0) atomicAdd(&psum[rbase + r], v);
    }
  }
  __syncthreads();

  for (int t = tid; t < BM; t += 512) atomicAdd(&part[r0 + t], psum[t]);
}

__global__ void rbf_finalize(float* __restrict__ part_out, const float* __restrict__ b, int n) {
  const int i = blockIdx.x * blockDim.x + threadIdx.x;
  if (i < n) {
    const float LOG2E = 1.44269504088896340736f;
    const float t = part_out[i] + b[0];
    part_out[i] = 1.0f / (1.0f + exp2f(-t * LOG2E));
  }
}

extern "C" void kernel_launch(void* const* d_in, const int* in_sizes, int n_in,
                              void* d_out, int out_size, void* d_ws, size_t ws_size,
                              hipStream_t stream) {
  const float* x    = (const float*)d_in[0];
  const float* cent = (const float*)d_in[1];
  const float* w    = (const float*)d_in[2];
  const float* b    = (const float*)d_in[3];
  float* out = (float*)d_out;

  // d_out doubles as the fp32 partial-sum accumulator (64 KB) -> no d_ws dependency.
  hipMemsetAsync(out, 0, (size_t)BATCH * sizeof(float), stream);

  dim3 grid(NCENT / BN, BATCH / BM);   // (32, 128)
  rbf_gemm<<<grid, 512, 0, stream>>>(x, cent, w, out);

  rbf_finalize<<<(BATCH + 255) / 256, 256, 0, stream>>>(out, b, BATCH);
}

// Round 2
// 94.719 us; speedup vs baseline: 1.7754x; 1.7754x over previous
//
#include <hip/hip_runtime.h>
#include <hip/hip_bf16.h>

// RBFNet forward, MI355X (gfx950).
// out[i] = sigmoid( b + sum_c w[c] * exp( x[i].c[c] - 0.5*(||x_i||^2 + ||c_c||^2) ) )
// Round 2: prep pass (fp32->bf16 + sumsq), dbuf BK=64 global_load_lds GEMM,
// XOR-swizzled LDS reads, XCD-aware block swizzle.

#define BATCH 16384
#define NCENT 4096
#define KDIM  256

using f32x4 = __attribute__((ext_vector_type(4))) float;
using s16x8 = __attribute__((ext_vector_type(8))) short;

#define AS1 __attribute__((address_space(1)))
#define AS3 __attribute__((address_space(3)))
#define GLOAD_LDS16(g, l) \
  __builtin_amdgcn_global_load_lds((const AS1 void*)(g), (AS3 void*)(l), 16, 0, 0)

__device__ __forceinline__ unsigned short f2bf(float f) {
  unsigned int u = __float_as_uint(f);
  return (unsigned short)((u + 0x7FFFu + ((u >> 16) & 1u)) >> 16);
}

// ---- prep: fp32 rows -> bf16 rows + per-row sum of squares (1 wave / row) ----
__global__ void rbf_prep(const float* __restrict__ src, unsigned short* __restrict__ dst,
                         float* __restrict__ sq) {
  const int row  = blockIdx.x * 4 + (threadIdx.x >> 6);
  const int lane = threadIdx.x & 63;
  const float4 v = ((const float4*)(src + (size_t)row * KDIM))[lane];
  float s = v.x * v.x + v.y * v.y + v.z * v.z + v.w * v.w;
  ushort4 u = { f2bf(v.x), f2bf(v.y), f2bf(v.z), f2bf(v.w) };
  ((ushort4*)(dst + (size_t)row * KDIM))[lane] = u;
#pragma unroll
  for (int o = 32; o; o >>= 1) s += __shfl_xor(s, o);
  if (lane == 0) sq[row] = s;
}

// ---- main: 128x128 tile, BK=64 double-buffered, 8 waves (2M x 4N) ----
__launch_bounds__(512, 4)   // 4 waves/EU -> 2 blocks/CU at 512 threads
__global__ void rbf_main(const unsigned short* __restrict__ xb,
                         const unsigned short* __restrict__ cb,
                         const float* __restrict__ xsqg,
                         const float* __restrict__ csqg,
                         const float* __restrict__ w,
                         float* __restrict__ part) {
  __shared__ unsigned short Ab[2][128 * 64];   // 2 x 16 KB, linear [row][k], row stride 128B
  __shared__ unsigned short Bb[2][128 * 64];
  __shared__ float xsqs[128], csqs[128], wsh[128], psum[128];

  // XCD-aware swizzle: xcd = bid&7 owns column-blocks [4*xcd .. 4*xcd+3];
  // consecutive chunks share the x row-block (L2 reuse of both operands).
  const int bid   = blockIdx.x;
  const int xcd   = bid & 7;
  const int chunk = bid >> 3;            // 0..511
  const int c0    = (xcd * 4 + (chunk & 3)) * 128;
  const int r0    = (chunk >> 2) * 128;

  const int tid  = threadIdx.x;
  const int wid  = tid >> 6, lane = tid & 63;
  const int wm   = wid >> 2, wn   = wid & 3;     // 2 x 4 wave grid
  const int lr   = lane & 15;                    // frag row/col
  const int kg   = lane >> 4;                    // k-group (8 bf16 per lane)

  if (tid < 128) {
    xsqs[tid] = xsqg[r0 + tid];
    csqs[tid] = csqg[c0 + tid];
    wsh[tid]  = w[c0 + tid];
    psum[tid] = 0.f;
  }

  // Staging: tile = 128 rows x 64 k = 1024 x 16B chunks; 8 waves x 2 instrs x 64 lanes.
  // LDS dest linear (chunk id = wid*128 + i*64 + lane); global source pre-swizzled:
  // LDS slot cs of row holds global slot cs ^ (row&7)  (st-16x32-style XOR, m173/T2).
  auto stage = [&](int buf, int t) {
#pragma unroll
    for (int i = 0; i < 2; ++i) {
      const int base = wid * 128 + i * 64;       // wave-uniform chunk base
      const int id   = base + lane;
      const int row  = id >> 3;
      const int gs   = (id & 7) ^ (row & 7);
      GLOAD_LDS16(xb + (size_t)(r0 + row) * KDIM + t * 64 + gs * 8, &Ab[buf][base * 8]);
      GLOAD_LDS16(cb + (size_t)(c0 + row) * KDIM + t * 64 + gs * 8, &Bb[buf][base * 8]);
    }
  };

  f32x4 acc[4][2];
#pragma unroll
  for (int m = 0; m < 4; ++m)
#pragma unroll
    for (int n = 0; n < 2; ++n)
      acc[m][n] = f32x4{0.f, 0.f, 0.f, 0.f};

  const int xorv = (lr & 7) << 4;   // rows in a frag differ only in lr; offsets are mult of 8

  stage(0, 0);
  __syncthreads();

#pragma unroll
  for (int t = 0; t < 4; ++t) {     // K = 256 = 4 x 64
    if (t < 3) stage((t + 1) & 1, t + 1);
    const int buf = t & 1;
    const char* Abase = (const char*)&Ab[buf][0];
    const char* Bbase = (const char*)&Bb[buf][0];
#pragma unroll
    for (int kk = 0; kk < 2; ++kk) {
      s16x8 af[4], bfr[2];
#pragma unroll
      for (int m = 0; m < 4; ++m) {
        const int row = wm * 64 + m * 16 + lr;
        af[m] = *(const s16x8*)(Abase + (row * 128 + (((kk * 4 + kg) << 4) ^ xorv)));
      }
#pragma unroll
      for (int n = 0; n < 2; ++n) {
        const int row = wn * 32 + n * 16 + lr;
        bfr[n] = *(const s16x8*)(Bbase + (row * 128 + (((kk * 4 + kg) << 4) ^ xorv)));
      }
#pragma unroll
      for (int m = 0; m < 4; ++m)
#pragma unroll
        for (int n = 0; n < 2; ++n)
          acc[m][n] = __builtin_amdgcn_mfma_f32_16x16x32_bf16(af[m], bfr[n], acc[m][n], 0, 0, 0);
    }
    __syncthreads();
  }

  // ---- epilogue: phi = exp(acc - 0.5*(xsq+csq)); v = w*phi; 16-lane row reduce ----
  const float LOG2E = 1.44269504088896340736f;
#pragma unroll
  for (int m = 0; m < 4; ++m) {
    const int rbase = wm * 64 + m * 16 + kg * 4;   // C/D: row = (lane>>4)*4 + reg
#pragma unroll
    for (int r = 0; r < 4; ++r) {
      const float hx = xsqs[rbase + r];
      float v = 0.f;
#pragma unroll
      for (int n = 0; n < 2; ++n) {
        const int col = wn * 32 + n * 16 + lr;     // C/D: col = lane&15
        const float e = acc[m][n][r] - 0.5f * (hx + csqs[col]);
        v += wsh[col] * exp2f(e * LOG2E);
      }
      v += __shfl_xor(v, 1);
      v += __shfl_xor(v, 2);
      v += __shfl_xor(v, 4);
      v += __shfl_xor(v, 8);
      if (lr == 0) atomicAdd(&psum[rbase + r], v);
    }
  }
  __syncthreads();

  for (int t2 = tid; t2 < 128; t2 += 512) atomicAdd(&part[r0 + t2], psum[t2]);
}

__global__ void rbf_finalize(float* __restrict__ part_out, const float* __restrict__ b, int n) {
  const int i = blockIdx.x * blockDim.x + threadIdx.x;
  if (i < n) {
    const float LOG2E = 1.44269504088896340736f;
    const float t = part_out[i] + b[0];
    part_out[i] = 1.0f / (1.0f + exp2f(-t * LOG2E));
  }
}

// ================= fallback (round-1 kernel) if ws too small =================
#define BM 128
#define BN 128
#define LDT 264

__launch_bounds__(512, 1)
__global__ void rbf_gemm_fb(const float* __restrict__ x,
                            const float* __restrict__ cent,
                            const float* __restrict__ w,
                            float* __restrict__ part) {
  __shared__ unsigned short As[BM][LDT];
  __shared__ unsigned short Bs[BN][LDT];
  __shared__ float xsq[BM], csq[BN], wsh[BN], psum[BM];

  const int tid = threadIdx.x;
  const int r0  = blockIdx.y * BM;
  const int c0  = blockIdx.x * BN;

  if (tid < BM) { xsq[tid] = 0.f; psum[tid] = 0.f; }
  else if (tid < BM + BN) { csq[tid - BM] = 0.f; }
  if (tid < BN) wsh[tid] = w[c0 + tid];
  __syncthreads();

  {
    const int row = tid >> 2, q = tid & 3;
    const float4* src = (const float4*)(x + (size_t)(r0 + row) * KDIM);
    float s = 0.f;
#pragma unroll
    for (int i = 0; i < 16; ++i) {
      const int c4 = q + 4 * i;
      float4 v = src[c4];
      s += v.x * v.x + v.y * v.y + v.z * v.z + v.w * v.w;
      ushort4 u = { f2bf(v.x), f2bf(v.y), f2bf(v.z), f2bf(v.w) };
      *(ushort4*)&As[row][c4 * 4] = u;
    }
    atomicAdd(&xsq[row], s);
  }
  {
    const int row = tid >> 2, q = tid & 3;
    const float4* src = (const float4*)(cent + (size_t)(c0 + row) * KDIM);
    float s = 0.f;
#pragma unroll
    for (int i = 0; i < 16; ++i) {
      const int c4 = q + 4 * i;
      float4 v = src[c4];
      s += v.x * v.x + v.y * v.y + v.z * v.z + v.w * v.w;
      ushort4 u = { f2bf(v.x), f2bf(v.y), f2bf(v.z), f2bf(v.w) };
      *(ushort4*)&Bs[row][c4 * 4] = u;
    }
    atomicAdd(&csq[row], s);
  }
  __syncthreads();

  const int wid = tid >> 6, lane = tid & 63;
  const int wm = wid >> 2, wn = wid & 3;
  const int lr = lane & 15, kg = lane >> 4;

  f32x4 acc[4][2];
#pragma unroll
  for (int m = 0; m < 4; ++m)
#pragma unroll
    for (int n = 0; n < 2; ++n)
      acc[m][n] = f32x4{0.f, 0.f, 0.f, 0.f};

#pragma unroll
  for (int ks = 0; ks < 8; ++ks) {
    const int kb = ks * 32 + kg * 8;
    s16x8 af[4], bfr[2];
#pragma unroll
    for (int m = 0; m < 4; ++m)
      af[m] = *(const s16x8*)&As[wm * 64 + m * 16 + lr][kb];
#pragma unroll
    for (int n = 0; n < 2; ++n)
      bfr[n] = *(const s16x8*)&Bs[wn * 32 + n * 16 + lr][kb];
#pragma unroll
    for (int m = 0; m < 4; ++m)
#pragma unroll
      for (int n = 0; n < 2; ++n)
        acc[m][n] = __builtin_amdgcn_mfma_f32_16x16x32_bf16(af[m], bfr[n], acc[m][n], 0, 0, 0);
  }

  const float LOG2E = 1.44269504088896340736f;
#pragma unroll
  for (int m = 0; m < 4; ++m) {
    const int rbase = wm * 64 + m * 16 + kg * 4;
#pragma unroll
    for (int r = 0; r < 4; ++r) {
      const float hx = xsq[rbase + r];
      float v = 0.f;
#pragma unroll
      for (int n = 0; n < 2; ++n) {
        const int col = wn * 32 + n * 16 + lr;
        const float e = acc[m][n][r] - 0.5f * (hx + csq[col]);
        v += wsh[col] * exp2f(e * LOG2E);
      }
      v += __shfl_xor(v, 1);
      v += __shfl_xor(v, 2);
      v += __shfl_xor(v, 4);
      v += __shfl_xor(v, 8);
      if (lr == 0) atomicAdd(&psum[rbase + r], v);
    }
  }
  __syncthreads();

  for (int t = tid; t < BM; t += 512) atomicAdd(&part[r0 + t], psum[t]);
}

extern "C" void kernel_launch(void* const* d_in, const int* in_sizes, int n_in,
                              void* d_out, int out_size, void* d_ws, size_t ws_size,
                              hipStream_t stream) {
  const float* x    = (const float*)d_in[0];
  const float* cent = (const float*)d_in[1];
  const float* w    = (const float*)d_in[2];
  const float* b    = (const float*)d_in[3];
  float* out = (float*)d_out;

  hipMemsetAsync(out, 0, (size_t)BATCH * sizeof(float), stream);

  const size_t xb_off  = 0;
  const size_t cb_off  = (size_t)BATCH * KDIM * 2;                 // 8 MB
  const size_t xsq_off = cb_off + (size_t)NCENT * KDIM * 2;        // +2 MB
  const size_t csq_off = xsq_off + (size_t)BATCH * 4;              // +64 KB
  const size_t needed  = csq_off + (size_t)NCENT * 4;              // +16 KB

  if (ws_size >= needed) {
    char* ws = (char*)d_ws;
    unsigned short* xb = (unsigned short*)(ws + xb_off);
    unsigned short* cb = (unsigned short*)(ws + cb_off);
    float* xsq = (float*)(ws + xsq_off);
    float* csq = (float*)(ws + csq_off);

    rbf_prep<<<BATCH / 4, 256, 0, stream>>>(x, xb, xsq);
    rbf_prep<<<NCENT / 4, 256, 0, stream>>>(cent, cb, csq);
    rbf_main<<<(BATCH / 128) * (NCENT / 128), 512, 0, stream>>>(xb, cb, xsq, csq, w, out);
  } else {
    dim3 grid(NCENT / BN, BATCH / BM);
    rbf_gemm_fb<<<grid, 512, 0, stream>>>(x, cent, w, out);
  }

  rbf_finalize<<<(BATCH + 255) / 256, 256, 0, stream>>>(out, b, BATCH);
}